// Round 1
// baseline (2541.657 us; speedup 1.0000x reference)
//
#include <hip/hip_runtime.h>

#define TOTAL_BITS 8

// ws layout (floats): [0..7] = per-f sum of squared quantization error
//                     [8] = step, [9] = scale, [10] = qmin, [11] = qmax

__global__ void fpq_init(float* ws) {
    if (threadIdx.x < 16) ws[threadIdx.x] = 0.0f;
}

__global__ __launch_bounds__(256) void fpq_mse(const float* __restrict__ x,
                                               float* __restrict__ ws,
                                               long long n) {
    float acc[TOTAL_BITS];
#pragma unroll
    for (int f = 0; f < TOTAL_BITS; ++f) acc[f] = 0.0f;

    const long long nvec = n >> 2;
    const float4* __restrict__ xv = (const float4*)x;
    const long long tid = (long long)blockIdx.x * blockDim.x + threadIdx.x;
    const long long stride = (long long)gridDim.x * blockDim.x;

    for (long long i = tid; i < nvec; i += stride) {
        float4 v = xv[i];
        float vals[4] = {v.x, v.y, v.z, v.w};
#pragma unroll
        for (int j = 0; j < 4; ++j) {
            float w = vals[j];
#pragma unroll
            for (int f = 0; f < TOTAL_BITS; ++f) {
                // all compile-time constants after full unroll
                const float scale = (float)(1 << f);          // 2^f
                const float step  = 1.0f / (float)(1 << f);   // 2^-f
                const float base  = (float)(1 << (TOTAL_BITS - 1 - f)); // 2^(b-1-f)
                const float qmin  = -base;
                const float qmax  = base - step;
                float c = fminf(fmaxf(w, qmin), qmax);
                float q = rintf(c * scale) * step;  // rintf = round-half-even, matches jnp.round
                float e = w - q;
                acc[f] = fmaf(e, e, acc[f]);
            }
        }
    }
    // scalar tail (n is a multiple of 4 here, but keep it correct in general)
    for (long long i = (nvec << 2) + tid; i < n; i += stride) {
        float w = x[i];
#pragma unroll
        for (int f = 0; f < TOTAL_BITS; ++f) {
            const float scale = (float)(1 << f);
            const float step  = 1.0f / (float)(1 << f);
            const float base  = (float)(1 << (TOTAL_BITS - 1 - f));
            const float qmin  = -base;
            const float qmax  = base - step;
            float c = fminf(fmaxf(w, qmin), qmax);
            float q = rintf(c * scale) * step;
            float e = w - q;
            acc[f] = fmaf(e, e, acc[f]);
        }
    }

    // wave-64 shuffle reduction, then one atomic per wave per f
#pragma unroll
    for (int f = 0; f < TOTAL_BITS; ++f) {
        float v = acc[f];
#pragma unroll
        for (int off = 32; off > 0; off >>= 1) v += __shfl_down(v, off, 64);
        if ((threadIdx.x & 63) == 0) atomicAdd(&ws[f], v);
    }
}

__global__ void fpq_select(float* ws) {
    // single thread: argmin over 8 candidates (first-min, matching jnp.argmin)
    int best = 0;
    float bm = ws[0];
    for (int f = 1; f < TOTAL_BITS; ++f) {
        float m = ws[f];
        if (m < bm) { bm = m; best = f; }
    }
    float scale = (float)(1 << best);
    float step  = 1.0f / scale;
    float base  = (float)(1 << (TOTAL_BITS - 1 - best));
    ws[8]  = step;
    ws[9]  = scale;
    ws[10] = -base;
    ws[11] = base - step;
}

__global__ __launch_bounds__(256) void fpq_quant(const float* __restrict__ x,
                                                 float* __restrict__ out,
                                                 const float* __restrict__ ws,
                                                 long long n) {
    const float step  = ws[8];
    const float scale = ws[9];
    const float qmin  = ws[10];
    const float qmax  = ws[11];

    const long long nvec = n >> 2;
    const float4* __restrict__ xv = (const float4*)x;
    float4* __restrict__ ov = (float4*)out;
    const long long tid = (long long)blockIdx.x * blockDim.x + threadIdx.x;
    const long long stride = (long long)gridDim.x * blockDim.x;

    for (long long i = tid; i < nvec; i += stride) {
        float4 v = xv[i];
        float4 o;
        o.x = rintf(fminf(fmaxf(v.x, qmin), qmax) * scale) * step;
        o.y = rintf(fminf(fmaxf(v.y, qmin), qmax) * scale) * step;
        o.z = rintf(fminf(fmaxf(v.z, qmin), qmax) * scale) * step;
        o.w = rintf(fminf(fmaxf(v.w, qmin), qmax) * scale) * step;
        ov[i] = o;
    }
    for (long long i = (nvec << 2) + tid; i < n; i += stride) {
        out[i] = rintf(fminf(fmaxf(x[i], qmin), qmax) * scale) * step;
    }
}

extern "C" void kernel_launch(void* const* d_in, const int* in_sizes, int n_in,
                              void* d_out, int out_size, void* d_ws, size_t ws_size,
                              hipStream_t stream) {
    const float* x = (const float*)d_in[0];
    float* out = (float*)d_out;
    float* ws = (float*)d_ws;
    const long long n = (long long)in_sizes[0];

    fpq_init<<<1, 64, 0, stream>>>(ws);
    fpq_mse<<<4096, 256, 0, stream>>>(x, ws, n);
    fpq_select<<<1, 1, 0, stream>>>(ws);
    fpq_quant<<<8192, 256, 0, stream>>>(x, out, ws, n);
}

// Round 2
// 1004.528 us; speedup vs baseline: 2.5302x; 2.5302x over previous
//
#include <hip/hip_runtime.h>

#define TOTAL_BITS 8
#define MSE_BLOCKS 2048

// ws layout (floats):
//   [8] = step, [9] = scale, [10] = qmin, [11] = qmax   (written by fpq_select)
//   [16 + 8*b + f] = block b's partial sum of squared error for candidate f

__global__ __launch_bounds__(256) void fpq_mse(const float* __restrict__ x,
                                               float* __restrict__ ws,
                                               long long n) {
    float acc[TOTAL_BITS];
#pragma unroll
    for (int f = 0; f < TOTAL_BITS; ++f) acc[f] = 0.0f;

    const long long nvec = n >> 2;
    const float4* __restrict__ xv = (const float4*)x;
    const long long tid = (long long)blockIdx.x * blockDim.x + threadIdx.x;
    const long long stride = (long long)gridDim.x * blockDim.x;

    for (long long i = tid; i < nvec; i += stride) {
        float4 v = xv[i];
        float vals[4] = {v.x, v.y, v.z, v.w};
#pragma unroll
        for (int j = 0; j < 4; ++j) {
            float w = vals[j];
#pragma unroll
            for (int f = 0; f < TOTAL_BITS; ++f) {
                // compile-time constants after unroll
                const float scale = (float)(1 << f);                    // 2^f
                const float step  = 1.0f / (float)(1 << f);             // 2^-f
                const float base  = (float)(1 << (TOTAL_BITS - 1 - f)); // 2^(b-1-f)
                const float qmin  = -base;
                const float qmax  = base - step;
                float c = fminf(fmaxf(w, qmin), qmax);   // v_med3
                float r = rintf(c * scale);              // round-half-even == jnp.round
                float e = fmaf(-r, step, w);             // w - r*step (q folded into fma)
                acc[f] = fmaf(e, e, acc[f]);
            }
        }
    }
    // scalar tail (defensive; n % 4 == 0 for this problem)
    for (long long i = (nvec << 2) + tid; i < n; i += stride) {
        float w = x[i];
#pragma unroll
        for (int f = 0; f < TOTAL_BITS; ++f) {
            const float scale = (float)(1 << f);
            const float step  = 1.0f / (float)(1 << f);
            const float base  = (float)(1 << (TOTAL_BITS - 1 - f));
            const float qmin  = -base;
            const float qmax  = base - step;
            float c = fminf(fmaxf(w, qmin), qmax);
            float r = rintf(c * scale);
            float e = fmaf(-r, step, w);
            acc[f] = fmaf(e, e, acc[f]);
        }
    }

    // wave-64 shuffle reduce -> LDS (shared-mem atomics, 32 per block) -> one
    // non-atomic global write of 8 partials per block. No global atomics.
    __shared__ float s[TOTAL_BITS];
    if (threadIdx.x < TOTAL_BITS) s[threadIdx.x] = 0.0f;
    __syncthreads();
#pragma unroll
    for (int f = 0; f < TOTAL_BITS; ++f) {
        float v = acc[f];
#pragma unroll
        for (int off = 32; off > 0; off >>= 1) v += __shfl_down(v, off, 64);
        if ((threadIdx.x & 63) == 0) atomicAdd(&s[f], v);
    }
    __syncthreads();
    if (threadIdx.x < TOTAL_BITS)
        ws[16 + 8 * (long long)blockIdx.x + threadIdx.x] = s[threadIdx.x];
}

__global__ void fpq_select(float* __restrict__ ws, int nblocks) {
    // one block, 256 threads: sum 8*nblocks partials, argmin, write constants
    __shared__ float s[TOTAL_BITS];
    if (threadIdx.x < TOTAL_BITS) s[threadIdx.x] = 0.0f;
    __syncthreads();
    const int f = threadIdx.x & 7;
    float acc = 0.0f;
    for (int b = threadIdx.x >> 3; b < nblocks; b += (int)blockDim.x >> 3)
        acc += ws[16 + 8 * (long long)b + f];
    atomicAdd(&s[f], acc);
    __syncthreads();
    if (threadIdx.x == 0) {
        int best = 0;
        float bm = s[0];
        for (int g = 1; g < TOTAL_BITS; ++g) {
            if (s[g] < bm) { bm = s[g]; best = g; }   // strict < == first-min (jnp.argmin)
        }
        float scale = (float)(1 << best);
        float step  = 1.0f / scale;
        float base  = (float)(1 << (TOTAL_BITS - 1 - best));
        ws[8]  = step;
        ws[9]  = scale;
        ws[10] = -base;
        ws[11] = base - step;
    }
}

__global__ __launch_bounds__(256) void fpq_quant(const float* __restrict__ x,
                                                 float* __restrict__ out,
                                                 const float* __restrict__ ws,
                                                 long long n) {
    const float step  = ws[8];
    const float scale = ws[9];
    const float qmin  = ws[10];
    const float qmax  = ws[11];

    const long long nvec = n >> 2;
    const float4* __restrict__ xv = (const float4*)x;
    float4* __restrict__ ov = (float4*)out;
    const long long tid = (long long)blockIdx.x * blockDim.x + threadIdx.x;
    const long long stride = (long long)gridDim.x * blockDim.x;

    for (long long i = tid; i < nvec; i += stride) {
        float4 v = xv[i];
        float4 o;
        o.x = rintf(fminf(fmaxf(v.x, qmin), qmax) * scale) * step;
        o.y = rintf(fminf(fmaxf(v.y, qmin), qmax) * scale) * step;
        o.z = rintf(fminf(fmaxf(v.z, qmin), qmax) * scale) * step;
        o.w = rintf(fminf(fmaxf(v.w, qmin), qmax) * scale) * step;
        ov[i] = o;
    }
    for (long long i = (nvec << 2) + tid; i < n; i += stride) {
        out[i] = rintf(fminf(fmaxf(x[i], qmin), qmax) * scale) * step;
    }
}

extern "C" void kernel_launch(void* const* d_in, const int* in_sizes, int n_in,
                              void* d_out, int out_size, void* d_ws, size_t ws_size,
                              hipStream_t stream) {
    const float* x = (const float*)d_in[0];
    float* out = (float*)d_out;
    float* ws = (float*)d_ws;
    const long long n = (long long)in_sizes[0];

    fpq_mse<<<MSE_BLOCKS, 256, 0, stream>>>(x, ws, n);
    fpq_select<<<1, 256, 0, stream>>>(ws, MSE_BLOCKS);
    fpq_quant<<<8192, 256, 0, stream>>>(x, out, ws, n);
}